// Round 1
// baseline (992.103 us; speedup 1.0000x reference)
//
#include <hip/hip_runtime.h>

// GCN 2-layer: N=100000 nodes, F=128 -> H=16 (relu) -> C=40, E=3200000 edges,
// PyG-style symmetric norm with self-loops.
//
// Pipeline (all fp32):
//  k_deg_init   : deg[i] = 1 (self loop)
//  k_deg_count  : deg[dst[e]] += 1 (atomic)
//  k_rsqrt      : dinv[i] = rsqrt(deg[i])   (deg >= 1 always, no zero guard)
//  k_gemm1      : h1 = x@W1 ; agg1 = dinv^2 * h1   (self-loop fused into init)
//  k_scatter1   : agg1[dst] += h1[src]*dinv[src]*dinv[dst]   (atomic, 16/edge)
//  k_layer2     : r = relu(agg1+b1); h2 = r@W2 ; out = b2 + dinv^2*h2
//  k_scatter2   : out[dst]  += h2[src]*dinv[src]*dinv[dst]   (atomic, 40/edge)

#define N_NODES 100000
#define F_IN    128
#define H_MID   16
#define C_OUT   40
#define N_EDGES 3200000

__global__ void k_deg_init(float* __restrict__ deg) {
    int i = blockIdx.x * 256 + threadIdx.x;
    if (i < N_NODES) deg[i] = 1.0f;           // self loop
}

__global__ void k_deg_count(const int* __restrict__ dst, float* __restrict__ deg) {
    int e = blockIdx.x * 256 + threadIdx.x;
    if (e < N_EDGES) atomicAdd(&deg[dst[e]], 1.0f);
}

__global__ void k_rsqrt(float* __restrict__ deg) {
    int i = blockIdx.x * 256 + threadIdx.x;
    if (i < N_NODES) deg[i] = rsqrtf(deg[i]);
}

// 16 nodes per block, 256 threads = 16 nodes x 16 out-features.
__global__ void __launch_bounds__(256) k_gemm1(
    const float* __restrict__ x, const float* __restrict__ W1,
    const float* __restrict__ dinv,
    float* __restrict__ h1, float* __restrict__ agg1) {
    __shared__ float w[F_IN * H_MID];   // 2048 floats, 8 KB
    __shared__ float xs[16 * 132];      // 16 rows padded to 132 (breaks 128-stride bank conflicts)
    int t = threadIdx.x;
    for (int i = t; i < F_IN * H_MID; i += 256) w[i] = W1[i];
    int tile = blockIdx.x;              // N/16 = 6250 tiles, exact
    const float4* xg = (const float4*)(x + (size_t)tile * 16 * F_IN);
    float4* xs4 = (float4*)xs;          // row stride 132 floats = 33 float4 (16B aligned)
    for (int i = t; i < 512; i += 256) {
        int r = i >> 5, c4 = i & 31;
        xs4[r * 33 + c4] = xg[r * 32 + c4];
    }
    __syncthreads();
    int node = t >> 4, j = t & 15;
    const float* xr = xs + node * 132;
    float acc = 0.f;
#pragma unroll 8
    for (int k = 0; k < F_IN; ++k) acc += xr[k] * w[k * H_MID + j];
    int g = tile * 16 + node;
    float dv = dinv[g];
    h1[(size_t)g * H_MID + j]   = acc;            // coalesced: t <-> consecutive (node,j)
    agg1[(size_t)g * H_MID + j] = acc * dv * dv;  // self-loop contribution as init
}

__global__ void k_scatter1(const int* __restrict__ src, const int* __restrict__ dst,
                           const float* __restrict__ dinv, const float* __restrict__ h1,
                           float* __restrict__ agg1) {
    unsigned tid = blockIdx.x * 256 + threadIdx.x;   // 16 lanes per edge
    unsigned e = tid >> 4;
    int j = tid & 15;
    if (e < N_EDGES) {
        int s = src[e], d = dst[e];
        float nrm = dinv[s] * dinv[d];
        atomicAdd(&agg1[(size_t)d * H_MID + j], h1[(size_t)s * H_MID + j] * nrm);
    }
}

// 16 nodes per block, 640 threads = 16 nodes x 40 classes.
__global__ void __launch_bounds__(640) k_layer2(
    const float* __restrict__ agg1, const float* __restrict__ b1,
    const float* __restrict__ W2, const float* __restrict__ b2,
    const float* __restrict__ dinv,
    float* __restrict__ h2, float* __restrict__ out) {
    __shared__ float w2[H_MID * C_OUT];  // 640
    __shared__ float r[16 * 17];         // padded
    int t = threadIdx.x;
    if (t < H_MID * C_OUT) w2[t] = W2[t];
    int tile = blockIdx.x;
    if (t < 256) {
        float v = agg1[(size_t)tile * 256 + t] + b1[t & 15];
        r[(t >> 4) * 17 + (t & 15)] = fmaxf(v, 0.f);
    }
    __syncthreads();
    int node = t / C_OUT, c = t % C_OUT;
    float acc = 0.f;
#pragma unroll
    for (int j = 0; j < H_MID; ++j) acc += r[node * 17 + j] * w2[j * C_OUT + c];
    int g = tile * 16 + node;
    float dv = dinv[g];
    h2[(size_t)g * C_OUT + c]  = acc;
    out[(size_t)g * C_OUT + c] = b2[c] + acc * dv * dv;  // bias + self loop as init
}

__global__ void k_scatter2(const int* __restrict__ src, const int* __restrict__ dst,
                           const float* __restrict__ dinv, const float* __restrict__ h2,
                           float* __restrict__ out) {
    unsigned tid = blockIdx.x * 256 + threadIdx.x;   // 40 lanes per edge
    unsigned e = tid / C_OUT;
    int c = tid % C_OUT;
    if (e < N_EDGES) {
        int s = src[e], d = dst[e];
        float nrm = dinv[s] * dinv[d];
        atomicAdd(&out[(size_t)d * C_OUT + c], h2[(size_t)s * C_OUT + c] * nrm);
    }
}

extern "C" void kernel_launch(void* const* d_in, const int* in_sizes, int n_in,
                              void* d_out, int out_size, void* d_ws, size_t ws_size,
                              hipStream_t stream) {
    const float* x  = (const float*)d_in[0];
    const int*   ei = (const int*)d_in[1];     // [2, E] flat: row 0 = src, row 1 = dst
    const float* W1 = (const float*)d_in[2];
    const float* b1 = (const float*)d_in[3];
    const float* W2 = (const float*)d_in[4];
    const float* b2 = (const float*)d_in[5];
    float* out = (float*)d_out;

    const int* src = ei;
    const int* dst = ei + N_EDGES;

    // workspace layout (floats): dinv[100352 pad] | h1[1.6M] | agg1[1.6M] | h2[4M]  ~= 29.2 MB
    float* ws_f = (float*)d_ws;
    float* dinv = ws_f;
    float* h1   = ws_f + 100352;
    float* agg1 = h1 + (size_t)N_NODES * H_MID;
    float* h2   = agg1 + (size_t)N_NODES * H_MID;

    const int B = 256;
    k_deg_init<<<(N_NODES + B - 1) / B, B, 0, stream>>>(dinv);
    k_deg_count<<<(N_EDGES + B - 1) / B, B, 0, stream>>>(dst, dinv);
    k_rsqrt<<<(N_NODES + B - 1) / B, B, 0, stream>>>(dinv);
    k_gemm1<<<N_NODES / 16, 256, 0, stream>>>(x, W1, dinv, h1, agg1);
    {
        long long threads = (long long)N_EDGES * H_MID;   // 51.2M
        k_scatter1<<<(unsigned)((threads + B - 1) / B), B, 0, stream>>>(src, dst, dinv, h1, agg1);
    }
    k_layer2<<<N_NODES / 16, 640, 0, stream>>>(agg1, b1, W2, b2, dinv, h2, out);
    {
        long long threads = (long long)N_EDGES * C_OUT;   // 128M
        k_scatter2<<<(unsigned)((threads + B - 1) / B), B, 0, stream>>>(src, dst, dinv, h2, out);
    }
}

// Round 2
// 633.419 us; speedup vs baseline: 1.5663x; 1.5663x over previous
//
#include <hip/hip_runtime.h>

// GCN 2-layer: N=100000, F=128 -> H=16 (relu) -> C=40, E=3200000.
// Key restructure vs R1: layer-2 aggregation moved into H=16 space:
//   out = A·(relu(agg1+b1)@W2) + b2  ==  (A·relu(agg1+b1))@W2 + b2
// so scatter2 handles 16 floats/edge (51.2M atomics) instead of 40 (128M).
// relu(agg1+b1) is computed on the fly in the scatter (VALU was 13% busy).
//
// Pipeline (fp32):
//  k_deg_init / k_deg_count / k_rsqrt : dinv = rsqrt(1 + indeg)
//  k_gemm1    : h1 = x@W1 ; agg1 = dinv^2*h1          (self-loop as init)
//  k_scatter1 : agg1[dst] += h1[src]*norm             (16/edge atomics)
//  k_init2    : agg2 = dinv^2 * relu(agg1+b1)         (self-loop as init)
//  k_scatter2 : agg2[dst] += relu(agg1[src]+b1)*norm  (16/edge atomics)
//  k_out      : out = agg2@W2 + b2

#define N_NODES 100000
#define F_IN    128
#define H_MID   16
#define C_OUT   40
#define N_EDGES 3200000

__global__ void k_deg_init(float* __restrict__ deg) {
    int i = blockIdx.x * 256 + threadIdx.x;
    if (i < N_NODES) deg[i] = 1.0f;           // self loop
}

__global__ void k_deg_count(const int* __restrict__ dst, float* __restrict__ deg) {
    int e = blockIdx.x * 256 + threadIdx.x;
    if (e < N_EDGES) atomicAdd(&deg[dst[e]], 1.0f);
}

__global__ void k_rsqrt(float* __restrict__ deg) {
    int i = blockIdx.x * 256 + threadIdx.x;
    if (i < N_NODES) deg[i] = rsqrtf(deg[i]);
}

// 16 nodes per block, 256 threads = 16 nodes x 16 out-features.
__global__ void __launch_bounds__(256) k_gemm1(
    const float* __restrict__ x, const float* __restrict__ W1,
    const float* __restrict__ dinv,
    float* __restrict__ h1, float* __restrict__ agg1) {
    __shared__ float w[F_IN * H_MID];   // 8 KB
    __shared__ float xs[16 * 132];      // padded rows: no 128-stride conflicts
    int t = threadIdx.x;
    for (int i = t; i < F_IN * H_MID; i += 256) w[i] = W1[i];
    int tile = blockIdx.x;              // 6250 tiles, exact
    const float4* xg = (const float4*)(x + (size_t)tile * 16 * F_IN);
    float4* xs4 = (float4*)xs;          // row stride 33 float4
    for (int i = t; i < 512; i += 256) {
        int r = i >> 5, c4 = i & 31;
        xs4[r * 33 + c4] = xg[r * 32 + c4];
    }
    __syncthreads();
    int node = t >> 4, j = t & 15;
    const float* xr = xs + node * 132;
    float acc = 0.f;
#pragma unroll 8
    for (int k = 0; k < F_IN; ++k) acc += xr[k] * w[k * H_MID + j];
    int g = tile * 16 + node;
    float dv = dinv[g];
    h1[(size_t)g * H_MID + j]   = acc;
    agg1[(size_t)g * H_MID + j] = acc * dv * dv;  // self-loop contribution
}

__global__ void k_scatter1(const int* __restrict__ src, const int* __restrict__ dst,
                           const float* __restrict__ dinv, const float* __restrict__ h1,
                           float* __restrict__ agg1) {
    unsigned tid = blockIdx.x * 256 + threadIdx.x;   // 16 lanes per edge
    unsigned e = tid >> 4;
    int j = tid & 15;
    if (e < N_EDGES) {
        int s = src[e], d = dst[e];
        float nrm = dinv[s] * dinv[d];
        atomicAdd(&agg1[(size_t)d * H_MID + j], h1[(size_t)s * H_MID + j] * nrm);
    }
}

// agg2 init with layer-2 self-loop: agg2 = dinv^2 * relu(agg1 + b1)
__global__ void k_init2(const float* __restrict__ agg1, const float* __restrict__ b1,
                        const float* __restrict__ dinv, float* __restrict__ agg2) {
    int i = blockIdx.x * 256 + threadIdx.x;          // over N*H = 1.6M
    if (i < N_NODES * H_MID) {
        float dv = dinv[i >> 4];
        float v = fmaxf(agg1[i] + b1[i & 15], 0.f);
        agg2[i] = v * dv * dv;
    }
}

__global__ void k_scatter2(const int* __restrict__ src, const int* __restrict__ dst,
                           const float* __restrict__ dinv, const float* __restrict__ agg1,
                           const float* __restrict__ b1, float* __restrict__ agg2) {
    unsigned tid = blockIdx.x * 256 + threadIdx.x;   // 16 lanes per edge
    unsigned e = tid >> 4;
    int j = tid & 15;
    if (e < N_EDGES) {
        int s = src[e], d = dst[e];
        float nrm = dinv[s] * dinv[d];
        float r = fmaxf(agg1[(size_t)s * H_MID + j] + b1[j], 0.f);  // relu on the fly
        atomicAdd(&agg2[(size_t)d * H_MID + j], r * nrm);
    }
}

// out = agg2@W2 + b2 : 16 nodes/block x 40 classes = 640 threads.
__global__ void __launch_bounds__(640) k_out(
    const float* __restrict__ agg2, const float* __restrict__ W2,
    const float* __restrict__ b2, float* __restrict__ out) {
    __shared__ float w2[H_MID * C_OUT];  // 640
    __shared__ float r[16 * 17];         // padded
    int t = threadIdx.x;
    if (t < H_MID * C_OUT) w2[t] = W2[t];
    int tile = blockIdx.x;
    if (t < 256) r[(t >> 4) * 17 + (t & 15)] = agg2[(size_t)tile * 256 + t];
    __syncthreads();
    int node = t / C_OUT, c = t % C_OUT;
    float acc = 0.f;
#pragma unroll
    for (int j = 0; j < H_MID; ++j) acc += r[node * 17 + j] * w2[j * C_OUT + c];
    int g = tile * 16 + node;
    out[(size_t)g * C_OUT + c] = b2[c] + acc;
}

extern "C" void kernel_launch(void* const* d_in, const int* in_sizes, int n_in,
                              void* d_out, int out_size, void* d_ws, size_t ws_size,
                              hipStream_t stream) {
    const float* x  = (const float*)d_in[0];
    const int*   ei = (const int*)d_in[1];     // [2, E]: row 0 = src, row 1 = dst
    const float* W1 = (const float*)d_in[2];
    const float* b1 = (const float*)d_in[3];
    const float* W2 = (const float*)d_in[4];
    const float* b2 = (const float*)d_in[5];
    float* out = (float*)d_out;

    const int* src = ei;
    const int* dst = ei + N_EDGES;

    // ws (floats): dinv[100352] | h1[1.6M] | agg1[1.6M] | agg2[1.6M]  ~= 19.6 MB
    float* ws_f = (float*)d_ws;
    float* dinv = ws_f;
    float* h1   = ws_f + 100352;
    float* agg1 = h1 + (size_t)N_NODES * H_MID;
    float* agg2 = agg1 + (size_t)N_NODES * H_MID;

    const int B = 256;
    k_deg_init<<<(N_NODES + B - 1) / B, B, 0, stream>>>(dinv);
    k_deg_count<<<(N_EDGES + B - 1) / B, B, 0, stream>>>(dst, dinv);
    k_rsqrt<<<(N_NODES + B - 1) / B, B, 0, stream>>>(dinv);
    k_gemm1<<<N_NODES / 16, 256, 0, stream>>>(x, W1, dinv, h1, agg1);
    {
        long long threads = (long long)N_EDGES * H_MID;   // 51.2M
        k_scatter1<<<(unsigned)((threads + B - 1) / B), B, 0, stream>>>(src, dst, dinv, h1, agg1);
    }
    k_init2<<<(N_NODES * H_MID + B - 1) / B, B, 0, stream>>>(agg1, b1, dinv, agg2);
    {
        long long threads = (long long)N_EDGES * H_MID;   // 51.2M
        k_scatter2<<<(unsigned)((threads + B - 1) / B), B, 0, stream>>>(src, dst, dinv, agg1, b1, agg2);
    }
    k_out<<<N_NODES / 16, 640, 0, stream>>>(agg2, W2, b2, out);
}